// Round 15
// baseline (167.834 us; speedup 1.0000x reference)
//
#include <hip/hip_runtime.h>
#include <math.h>

#define NI   32
#define NH   1024
#define NB   1024

// ws layout. g-axis (h2) degree-SORTED; h1-axis natural. W2/W1 stored as BF16.
//   fp32: b1s[1056] @0, b2s[1024] @1056, W3s[64][1024] @2080
//   W1B  (uint)  @67616 : W1B[k][su] = bf16(W1m[j=2k][su]) | bf16(W1m[2k+1][su])<<16
//   PB   (uint4) @84512 : panel dd, pair u2, sg-quad Q, halves r=0/1
#define OFF_B1S 0
#define OFF_B2S 1056
#define OFF_W3S 2080
#define OFF_W1B 67616            // float-index (4B units)
#define OFF_PB  84512            // float-index; PB block idx = (dd*17+u2)*256 + Q

__device__ __forceinline__ int base_of(int d) { return (d == 0) ? 0 : 33 * d + 1; }

__device__ __forceinline__ unsigned short f2bf(float f) {   // RNE bf16
    unsigned u = __float_as_uint(f);
    return (unsigned short)((u + 0x7FFFu + ((u >> 16) & 1u)) >> 16);
}
__device__ __forceinline__ float bflo(unsigned u) { return __uint_as_float(u << 16); }
__device__ __forceinline__ float bfhi(unsigned u) { return __uint_as_float(u & 0xFFFF0000u); }

// Raw barrier draining LDS only (lgkmcnt=0), vmcnt left open: prefetched
// global loads stay in flight across the barrier. Proven correct in R12.
__device__ __forceinline__ void barrier_lgkm() {
    __builtin_amdgcn_s_waitcnt(0xC07F);     // vmcnt=63, expcnt=7, lgkmcnt=0
    __builtin_amdgcn_s_barrier();
}

// ---- prep (identical to R13/R14) ----
template <int CNT>
__device__ __forceinline__ void prep_w2_cls(int d, int oh0, const float* __restrict__ W2,
                                            unsigned short* __restrict__ pb16, int t,
                                            float (*tile)[65]) {
    const int bse = base_of(d);
#pragma unroll 1
    for (int e = t; e < CNT * 64; e += 256) {
        int k = e >> 6, c = e & 63;
        int og = d + 31 * k;
        tile[k][c] = W2[(size_t)og * NH + oh0 + c];
    }
    __syncthreads();
#pragma unroll 1
    for (int e = t; e < 64 * CNT; e += 256) {
        int oh_l = e / CNT;
        int k = e - oh_l * CNT;
        int oh = oh0 + oh_l;
        int dd = oh % 31, u = oh / 31;
        int sg = bse + k;
        float v = (d >= dd) ? tile[k][oh_l] : 0.0f;
        size_t a = (size_t)((dd * 17 + (u >> 1)) * 256 + (sg >> 2)) * 8
                 + (u & 1) * 4 + (sg & 3);
        pb16[a] = f2bf(v);
    }
}

template <int CNT>
__device__ __forceinline__ void prep_small_cls(int d, const float* __restrict__ W1,
        const float* __restrict__ b1, const float* __restrict__ b2,
        const float* __restrict__ W3, float* __restrict__ ws, int t) {
    const int bse = base_of(d);
    unsigned short* w1b16 = (unsigned short*)(ws + OFF_W1B);
#pragma unroll 1
    for (int e = t; e < 64 * CNT; e += 256) {
        int o = e / CNT, k = e - o * CNT;
        int og = d + 31 * k;
        float v = (((o & 31) - 1) >= d) ? W3[(size_t)o * NH + og] : 0.0f;
        ws[OFF_W3S + (size_t)o * NH + bse + k] = v;
    }
#pragma unroll 1
    for (int e = t; e < 32 * CNT; e += 256) {
        int j = e / CNT, k = e - j * CNT;
        int og = d + 31 * k;
        int su = bse + k;
        float v = (d >= j) ? W1[og * NI + j] : 0.0f;
        w1b16[(size_t)((j >> 1) * 1056 + su) * 2 + (j & 1)] = f2bf(v);
    }
    if (t < CNT) {
        int og = d + 31 * t;
        ws[OFF_B1S + bse + t] = b1[og];
        ws[OFF_B2S + bse + t] = b2[og];
    }
}

__global__ __launch_bounds__(256) void prep_all(const float* __restrict__ W1,
        const float* __restrict__ b1, const float* __restrict__ W2,
        const float* __restrict__ b2, const float* __restrict__ W3,
        float* __restrict__ ws) {
    __shared__ float tile[34][65];
    const int bid = blockIdx.x, t = threadIdx.x;
    unsigned short* pb16 = (unsigned short*)(ws + OFF_PB);
    if (bid < 496) {
        int d = bid >> 4, oh0 = (bid & 15) * 64;
        if (d == 0) prep_w2_cls<34>(0, oh0, W2, pb16, t, tile);
        else        prep_w2_cls<33>(d, oh0, W2, pb16, t, tile);
    } else {
        int d = bid - 496;
        if (d == 0) prep_small_cls<34>(0, W1, b1, b2, W3, ws, t);
        else        prep_small_cls<33>(d, W1, b1, b2, W3, ws, t);
    }
}

// consume one bf16 pair-load; coefficients from a 16B broadcast LDS read:
// av = { a0[2u2], a1[2u2], a0[2u2+1], a1[2u2+1] }
__device__ __forceinline__ void consume_pair(uint4 g, float4 av,
                                             float4& acc0, float4& acc1) {
    float f0 = bflo(g.x), f1 = bfhi(g.x), f2 = bflo(g.y), f3 = bfhi(g.y);
    float f4 = bflo(g.z), f5 = bfhi(g.z), f6 = bflo(g.w), f7 = bfhi(g.w);
    acc0.x = fmaf(av.x, f0, acc0.x); acc0.y = fmaf(av.x, f1, acc0.y);
    acc0.z = fmaf(av.x, f2, acc0.z); acc0.w = fmaf(av.x, f3, acc0.w);
    acc1.x = fmaf(av.y, f0, acc1.x); acc1.y = fmaf(av.y, f1, acc1.y);
    acc1.z = fmaf(av.y, f2, acc1.z); acc1.w = fmaf(av.y, f3, acc1.w);
    acc0.x = fmaf(av.z, f4, acc0.x); acc0.y = fmaf(av.z, f5, acc0.y);
    acc0.z = fmaf(av.z, f6, acc0.z); acc0.w = fmaf(av.z, f7, acc0.w);
    acc1.x = fmaf(av.w, f4, acc1.x); acc1.y = fmaf(av.w, f5, acc1.y);
    acc1.z = fmaf(av.w, f6, acc1.z); acc1.w = fmaf(av.w, f7, acc1.w);
}

// R15 = R14 + (1) cross-step W1B prefetch (wk[16] loop-carried, issued before
// the barrier), (2) lgkm-only barrier so those loads ride through
// barrier+combine, (3) rcp-based tanh (1 instr vs IEEE divide sequence).
__global__ __launch_bounds__(256, 2) void made_scan(
        const float* __restrict__ inputs,
        const float* __restrict__ b3,
        const float* __restrict__ ws,
        float* __restrict__ out) {
    __shared__ float xsS[4][2][36];     // per-wave private x (pad 36)
    __shared__ float a1S[4][36][2];     // per-wave private a1 [unit][row]
    __shared__ float part[2][4][4];
    __shared__ float b3S[64];
    __shared__ float xinS[2][NI];

    const int lane = threadIdx.x & 63;
    const int w    = threadIdx.x >> 6;
    const int pairity = ((blockIdx.x >> 8) ^ blockIdx.x) & 1;
    const int q    = w ^ (pairity * 3);
    const int gb   = q * 256;
    const int row0 = blockIdx.x * 2;

    const float* b1s = ws + OFF_B1S;
    const float* b2s = ws + OFF_B2S;
    const float* W3s = ws + OFF_W3S;
    const unsigned* W1B = (const unsigned*)(ws + OFF_W1B);
    const uint4*    PB  = (const uint4*)(ws + OFF_PB);

    float4 acc0 = ((const float4*)(b2s + gb))[lane];
    float4 acc1 = acc0;
    float J0 = 0.f, J1 = 0.f;

    if (w == 0) {
        b3S[lane] = b3[lane];
        if (lane < NI) {
            xinS[0][lane] = inputs[row0 * NI + lane];
            xinS[1][lane] = inputs[(row0 + 1) * NI + lane];
        }
    }
    {
        float* px = &xsS[w][0][0];
        for (int k = lane; k < 72; k += 64) px[k] = 0.f;
    }

    unsigned wk[16];                    // W1B taps, prefetched cross-step
#pragma unroll
    for (int k = 0; k < 16; ++k) wk[k] = W1B[k * 1056 + lane];  // i=1: su=lane
    __syncthreads();

    // step 0: W3 rows 0/32 fully masked -> p = (b3[0], b3[32])
    {
        float p00 = b3S[0], p01 = b3S[NI];
        float e20 = __expf(2.f * fminf(p01, 15.f));
        float ta  = fmaf(-2.f, __builtin_amdgcn_rcpf(e20 + 1.f), 1.f);
        float es  = __expf(ta);
        float x0  = fmaf(xinS[0][0], es, p00);
        float x1  = fmaf(xinS[1][0], es, p00);
        J0 -= ta; J1 -= ta;
        if (lane == 0) { xsS[w][0][0] = x0; xsS[w][1][0] = x1; }
    }

#pragma unroll 1
    for (int i = 1; i < NI; ++i) {
        const int dd   = i - 1;
        const int goff = base_of(dd);
        const int cnt  = (i == 1) ? 34 : 33;
        const bool doB = (gb + 256 > goff);
        const bool doC = (gb < 33 * i + 1);

        float4 wa = make_float4(0, 0, 0, 0), wb = make_float4(0, 0, 0, 0);
        if (doC) {
            wa = ((const float4*)(W3s + (size_t)i * NH + gb))[lane];
            wb = ((const float4*)(W3s + (size_t)(NI + i) * NH + gb))[lane];
        }

        if (doB) {
            const uint4* pbase = PB + (size_t)(dd * 17) * 256 + (gb >> 2) + lane;
            uint4 G1[9];
#pragma unroll
            for (int u2 = 0; u2 < 9; ++u2) G1[u2] = pbase[u2 * 256];
            __builtin_amdgcn_sched_barrier(0);

            // Phase A: 32 taps; x from private LDS broadcast, W1 from wk
            // (prefetched LAST step -> resident). Taps j>=i exact zeros.
            float bz = b1s[goff + lane];
            float zA0 = bz, zA1 = 0, zA2 = 0, zA3 = 0;
            float zB0 = bz, zB1 = 0, zB2 = 0, zB3 = 0;
#pragma unroll
            for (int j4 = 0; j4 < 8; ++j4) {
                float4 xq0 = *(const float4*)&xsS[w][0][4 * j4];
                float4 xq1 = *(const float4*)&xsS[w][1][4 * j4];
                float w0 = bflo(wk[2 * j4]),     w1 = bfhi(wk[2 * j4]);
                float w2 = bflo(wk[2 * j4 + 1]), w3 = bfhi(wk[2 * j4 + 1]);
                zA0 = fmaf(xq0.x, w0, zA0); zB0 = fmaf(xq1.x, w0, zB0);
                zA1 = fmaf(xq0.y, w1, zA1); zB1 = fmaf(xq1.y, w1, zB1);
                zA2 = fmaf(xq0.z, w2, zA2); zB2 = fmaf(xq1.z, w2, zB2);
                zA3 = fmaf(xq0.w, w3, zA3); zB3 = fmaf(xq1.w, w3, zB3);
            }
            const bool ok = lane < cnt;
            float a0 = ok ? fmaxf((zA0 + zA1) + (zA2 + zA3), 0.f) : 0.f;
            float a1 = ok ? fmaxf((zB0 + zB1) + (zB2 + zB3), 0.f) : 0.f;
            if (lane < 36) {
                float2 v = make_float2(a0, a1);
                *(float2*)&a1S[w][lane][0] = v;
            }
            __builtin_amdgcn_sched_barrier(0);

            uint4 G2[8];
#pragma unroll
            for (int u2 = 0; u2 < 8; ++u2) G2[u2] = pbase[(9 + u2) * 256];
            __builtin_amdgcn_sched_barrier(0);
#pragma unroll
            for (int u2 = 0; u2 < 9; ++u2)
                consume_pair(G1[u2], *(const float4*)&a1S[w][2 * u2][0], acc0, acc1);
            __builtin_amdgcn_sched_barrier(0);
#pragma unroll
            for (int u2 = 0; u2 < 8; ++u2)
                consume_pair(G2[u2], *(const float4*)&a1S[w][18 + 2 * u2][0], acc0, acc1);
        }

        // Phase C (fp32 W3; zeros beyond prefix keep it exact)
        float s00 = 0, s01 = 0, s10 = 0, s11 = 0;
        if (doC) {
            float hx, hy, hz, hw;
            hx = fmaxf(acc0.x, 0.f); hy = fmaxf(acc0.y, 0.f);
            hz = fmaxf(acc0.z, 0.f); hw = fmaxf(acc0.w, 0.f);
            s00 = fmaf(wa.x, hx, fmaf(wa.y, hy, fmaf(wa.z, hz, wa.w * hw)));
            s01 = fmaf(wb.x, hx, fmaf(wb.y, hy, fmaf(wb.z, hz, wb.w * hw)));
            hx = fmaxf(acc1.x, 0.f); hy = fmaxf(acc1.y, 0.f);
            hz = fmaxf(acc1.z, 0.f); hw = fmaxf(acc1.w, 0.f);
            s10 = fmaf(wa.x, hx, fmaf(wa.y, hy, fmaf(wa.z, hz, wa.w * hw)));
            s11 = fmaf(wb.x, hx, fmaf(wb.y, hy, fmaf(wb.z, hz, wb.w * hw)));
#pragma unroll
            for (int m = 32; m >= 1; m >>= 1) {
                s00 += __shfl_xor(s00, m, 64); s01 += __shfl_xor(s01, m, 64);
                s10 += __shfl_xor(s10, m, 64); s11 += __shfl_xor(s11, m, 64);
            }
        }
        if (lane == 0)
            *((float4*)&part[i & 1][w][0]) = make_float4(s00, s01, s10, s11);

        // ---- cross-step W1B prefetch (next dd = i -> goff_n = base_of(i));
        // issued BEFORE the lgkm-only barrier: stays in flight through
        // barrier + combine, resident by next phase A.
        {
            const int goff_n = base_of(i);
            if (i < NI - 1 && gb + 256 > goff_n) {
                const int su_n = goff_n + lane;
#pragma unroll
                for (int k = 0; k < 16; ++k) wk[k] = W1B[k * 1056 + su_n];
            }
        }
        barrier_lgkm();

        // combine — replicated in every wave; x published to own-wave xs only
        const float* pb = &part[i & 1][0][0];
        float4 q0 = ((const float4*)pb)[0], q1 = ((const float4*)pb)[1];
        float4 q2 = ((const float4*)pb)[2], q3 = ((const float4*)pb)[3];
        float bi  = b3S[i];
        float bia = b3S[NI + i];
        float p00 = ((q0.x + q1.x) + (q2.x + q3.x)) + bi;
        float p01 = ((q0.y + q1.y) + (q2.y + q3.y)) + bia;
        float p10 = ((q0.z + q1.z) + (q2.z + q3.z)) + bi;
        float p11 = ((q0.w + q1.w) + (q2.w + q3.w)) + bia;
        float e20 = __expf(2.f * fminf(p01, 15.f));
        float ta0 = fmaf(-2.f, __builtin_amdgcn_rcpf(e20 + 1.f), 1.f);
        float x0  = fmaf(xinS[0][i], __expf(ta0), p00);
        float e21 = __expf(2.f * fminf(p11, 15.f));
        float ta1 = fmaf(-2.f, __builtin_amdgcn_rcpf(e21 + 1.f), 1.f);
        float x1  = fmaf(xinS[1][i], __expf(ta1), p10);
        J0 -= ta0; J1 -= ta1;
        if (lane == 0) { xsS[w][0][i] = x0; xsS[w][1][i] = x1; }
    }

    if (w == 0) {
        if (lane < NI) {
            out[row0 * NI + lane]       = xsS[0][0][lane];
            out[(row0 + 1) * NI + lane] = xsS[0][1][lane];
        }
        if (lane == 0) {
            out[NB * NI + row0]     = J0;
            out[NB * NI + row0 + 1] = J1;
        }
    }
}

extern "C" void kernel_launch(void* const* d_in, const int* in_sizes, int n_in,
                              void* d_out, int out_size, void* d_ws, size_t ws_size,
                              hipStream_t stream) {
    const float* inputs = (const float*)d_in[0];
    const float* W1     = (const float*)d_in[1];
    const float* b1     = (const float*)d_in[2];
    const float* W2     = (const float*)d_in[3];
    const float* b2     = (const float*)d_in[4];
    const float* W3     = (const float*)d_in[5];
    const float* b3     = (const float*)d_in[6];
    float* out = (float*)d_out;
    float* ws  = (float*)d_ws;

    prep_all<<<527, 256, 0, stream>>>(W1, b1, W2, b2, W3, ws);
    made_scan<<<NB / 2, 256, 0, stream>>>(inputs, b3, ws, out);
}